// Round 1
// 626.151 us; speedup vs baseline: 1.0009x; 1.0009x over previous
//
#include <hip/hip_runtime.h>
#include <math.h>

#define N_ENT 100000
#define KNBR 64
#define DHALF 500
#define TWO_D 1000
#define ATTN_DIM 128
#define NREL 237
#define ETA_MAX 0.5f

// ---------------------------------------------------------------------------
// Kernel T: cos/sin table for all relation phases (948 KB, L2-resident).
// Replaces 16M on-device __sincosf in the hot kernel with L2 float4 loads.
// ---------------------------------------------------------------------------
__global__ __launch_bounds__(256) void build_trig(
    const float* __restrict__ P, float* __restrict__ CS)
{
    int idx = blockIdx.x * 256 + threadIdx.x;
    if (idx < NREL * DHALF) {
        float s, c;
        sincosf(P[idx], &s, &c);   // precise: matches jnp.cos/sin closely
        CS[2 * idx]     = c;       // interleaved (cos, sin) per dim
        CS[2 * idx + 1] = s;
    }
}

// ---------------------------------------------------------------------------
// Kernel A: per-anchor attention-score vector  M[b,:] = (Wk^T (Wq e_i))/sqrt(A)
// 4 anchors/block -> 256 blocks (fills all 256 CUs; previous 128-block grid
// left half the GPU idle). Wq/Wk (0.5 MB each) stay L2-resident.
// ---------------------------------------------------------------------------
__global__ __launch_bounds__(256) void precompute_m(
    const int* __restrict__ anchor_ids,
    const float* __restrict__ E,
    const float* __restrict__ Wq,
    const float* __restrict__ Wk,
    float* __restrict__ M, int B)
{
    __shared__ float e_lds[4][TWO_D];     // 16 KB
    __shared__ float qp[2][4][ATTN_DIM];  // 4 KB (two half-d partials)
    __shared__ float q_lds[4][ATTN_DIM];  // 2 KB
    const int t  = threadIdx.x;
    const int b0 = blockIdx.x * 4;

    // stage 4 anchor embeddings (rows are 4000 B, 16B-aligned -> float4)
    for (int j = 0; j < 4; ++j) {
        int bb = b0 + j;
        int row = (bb < B) ? anchor_ids[bb] : 0;
        if (t < 250) {
            float4 v = ((const float4*)(E + (size_t)row * TWO_D))[t];
            ((float4*)&e_lds[j][0])[t] = v;
        }
    }
    __syncthreads();

    // GEMM1: q[j][a] = sum_d e[j][d] * Wq[a][d]; d split into two halves.
    // Per-thread row walk: lines stay L1-resident (128 rows x 64 B = 8 KB).
    {
        const int a = t & 127;
        const int h = t >> 7;
        float acc[4] = {0.f, 0.f, 0.f, 0.f};
        const float* wrow = Wq + (size_t)a * TWO_D + h * DHALF;
        const int base = h * DHALF;
        for (int d = 0; d < DHALF; ++d) {
            float w = wrow[d];
            int dd = base + d;
#pragma unroll
            for (int j = 0; j < 4; ++j) acc[j] += w * e_lds[j][dd];
        }
#pragma unroll
        for (int j = 0; j < 4; ++j) qp[h][j][a] = acc[j];
    }
    __syncthreads();
    for (int idx = t; idx < 4 * ATTN_DIM; idx += 256)
        ((float*)q_lds)[idx] = ((float*)qp)[idx] + ((float*)qp)[4 * ATTN_DIM + idx];
    __syncthreads();

    // GEMM2: m[j][d] = sum_a q[j][a] * Wk[a][d]; thread t owns d = t + 256c
    const float inv_scale = 0.0883883476483184f;  // 1/sqrt(128)
    float acc2[4][4];
#pragma unroll
    for (int c = 0; c < 4; ++c)
#pragma unroll
        for (int j = 0; j < 4; ++j) acc2[c][j] = 0.f;

    for (int a = 0; a < ATTN_DIM; ++a) {
        const float* wkrow = Wk + (size_t)a * TWO_D;
        float wk[4];
#pragma unroll
        for (int c = 0; c < 4; ++c) {
            int d = t + 256 * c;
            wk[c] = (d < TWO_D) ? wkrow[d] : 0.f;  // coalesced
        }
#pragma unroll
        for (int j = 0; j < 4; ++j) {
            float qv = q_lds[j][a];  // LDS broadcast
#pragma unroll
            for (int c = 0; c < 4; ++c) acc2[c][j] += qv * wk[c];
        }
    }
#pragma unroll
    for (int c = 0; c < 4; ++c) {
        int d = t + 256 * c;
        if (d < TWO_D) {
#pragma unroll
            for (int j = 0; j < 4; ++j) {
                int bb = b0 + j;
                if (bb < B) M[(size_t)bb * TWO_D + d] = acc2[c][j] * inv_scale;
            }
        }
    }
}

// ---------------------------------------------------------------------------
// Kernel B: one block per anchor, max-free online softmax (logits O(0.1)).
// v2 changes vs previous round:
//   - rel_phase sincos replaced by table lookup (trans pipe off critical path)
//   - all gathers are float4 (16 B/lane); lane l owns dims 4l..4l+3 (chunk 0)
//     and 256+4l..259+4l (chunk 1, lanes 0..60)
//   - ballot-compacted active-neighbor list: waves get ceil/floor(n/4)
//     neighbors each (was Binomial(16,.5) imbalance -> barrier tail waste)
//   - explicit 2-deep register double-buffer: neighbor k+4's 8 float4 loads
//     are in flight during neighbor k's rotate/dot/softmax compute
// ---------------------------------------------------------------------------
__global__ __launch_bounds__(256, 4) void refine(
    const int* __restrict__ anchor_ids,
    const int* __restrict__ nbr_ent,
    const int* __restrict__ nbr_rel,
    const int* __restrict__ nbr_dir,
    const int* __restrict__ nbr_mask,
    const float* __restrict__ freq,
    const float* __restrict__ E,
    const float* __restrict__ CS,
    const float* __restrict__ a_param,
    const float* __restrict__ eta_raw_p,
    const float* __restrict__ w_raw_p,
    const float* __restrict__ b_p,
    const float* __restrict__ rel_bias,
    const float* __restrict__ dir_bias,
    const float* __restrict__ M,
    float* __restrict__ out)
{
    __shared__ float accm[4][TWO_D];   // 16 KB merge buffer
    __shared__ float sum_s[4];
    __shared__ int ent_s[KNBR], rel_s[KNBR], dir_s[KNBR], list_s[KNBR];
    __shared__ int cnt_s;

    const int t = threadIdx.x;
    const int bid = blockIdx.x;
    const int anchor = anchor_ids[bid];
    const int lane = t & 63;
    const int wid = t >> 6;
    const int l1 = (lane < 61) ? lane : 60;  // chunk-1 covers 244 dims = 61 lanes

    // stage neighbor metadata + build compacted active list (wave 0 only)
    if (t < KNBR) {
        size_t off = (size_t)anchor * KNBR + t;
        int e = nbr_ent[off];
        int r = nbr_rel[off];
        int d = nbr_dir[off];
        int m = nbr_mask[off];
        ent_s[t] = e; rel_s[t] = r; dir_s[t] = d;
        unsigned long long bal = __ballot(m != 0);
        if (m) list_s[__popcll(bal & ((1ull << t) - 1))] = t;
        if (t == 0) cnt_s = __popcll(bal);
    }

    // lane-local M fragments, straight from global (row is L2-hot, read 4x)
    const float4* Mr = (const float4*)(M + (size_t)bid * TWO_D);
    float4 mre0 = Mr[lane];
    float4 mim0 = Mr[125 + lane];       // im half starts at float 500 (16B-aligned)
    float4 mre1 = Mr[64 + l1];
    float4 mim1 = Mr[189 + l1];
    if (lane >= 61) {                   // dead chunk-1 lanes contribute 0 to dot
        mre1 = make_float4(0.f, 0.f, 0.f, 0.f);
        mim1 = make_float4(0.f, 0.f, 0.f, 0.f);
    }
    float mreA[8] = {mre0.x, mre0.y, mre0.z, mre0.w, mre1.x, mre1.y, mre1.z, mre1.w};
    float mimA[8] = {mim0.x, mim0.y, mim0.z, mim0.w, mim1.x, mim1.y, mim1.z, mim1.w};

    float accre[8], accim[8];
#pragma unroll
    for (int q = 0; q < 8; ++q) { accre[q] = 0.f; accim[q] = 0.f; }
    float wsum = 0.f;
    const float db0 = dir_bias[0];
    const float db1 = dir_bias[1];

    __syncthreads();
    const int n = cnt_s;

    struct NB {
        float4 re0, im0, re1, im1;   // entity embedding fragments
        float4 csA, csB, csC, csD;   // interleaved (cos,sin) fragments
        float bias, sgn;
    };
    NB A, Bq;

    auto load_nb = [&](NB& nb, int slot) {
        int k = list_s[slot];
        int df = dir_s[k];
        const float4* er = (const float4*)(E + (size_t)ent_s[k] * TWO_D);
        const float4* cr = (const float4*)(CS + (size_t)rel_s[k] * TWO_D);
        nb.re0 = er[lane];          nb.im0 = er[125 + lane];
        nb.re1 = er[64 + l1];       nb.im1 = er[189 + l1];
        nb.csA = cr[2 * lane];      nb.csB = cr[2 * lane + 1];
        nb.csC = cr[128 + 2 * l1];  nb.csD = cr[129 + 2 * l1];
        nb.bias = rel_bias[rel_s[k]] + (df ? db1 : db0);
        nb.sgn = df ? -1.f : 1.f;   // RotatE conjugate for reverse edges
    };

    auto compute_nb = [&](const NB& nb) {
        float re_[8] = {nb.re0.x, nb.re0.y, nb.re0.z, nb.re0.w,
                        nb.re1.x, nb.re1.y, nb.re1.z, nb.re1.w};
        float im_[8] = {nb.im0.x, nb.im0.y, nb.im0.z, nb.im0.w,
                        nb.im1.x, nb.im1.y, nb.im1.z, nb.im1.w};
        float cc[8]  = {nb.csA.x, nb.csA.z, nb.csB.x, nb.csB.z,
                        nb.csC.x, nb.csC.z, nb.csD.x, nb.csD.z};
        float ssv[8] = {nb.csA.y, nb.csA.w, nb.csB.y, nb.csB.w,
                        nb.csC.y, nb.csC.w, nb.csD.y, nb.csD.w};
        float hre[8], him[8];
        float dot = 0.f;
#pragma unroll
        for (int q = 0; q < 8; ++q) {
            float sv = ssv[q] * nb.sgn;
            hre[q] = re_[q] * cc[q] - im_[q] * sv;
            him[q] = re_[q] * sv + im_[q] * cc[q];
            dot += mreA[q] * hre[q] + mimA[q] * him[q];
        }
        // 64-lane butterfly: every lane gets the full dot
        dot += __shfl_xor(dot, 32);
        dot += __shfl_xor(dot, 16);
        dot += __shfl_xor(dot, 8);
        dot += __shfl_xor(dot, 4);
        dot += __shfl_xor(dot, 2);
        dot += __shfl_xor(dot, 1);
        float p = __expf(dot + nb.bias);  // |logit| ~ 0.2 -> no max needed
        wsum += p;
#pragma unroll
        for (int q = 0; q < 8; ++q) {
            accre[q] += p * hre[q];
            accim[q] += p * him[q];
        }
    };

    // 2-deep software pipeline over this wave's slice of the compacted list
    {
        int i = wid;
        bool haveA = (i < n);
        if (haveA) load_nb(A, i);
        while (haveA) {
            int iB = i + 4;
            bool haveB = (iB < n);
            if (haveB) load_nb(Bq, iB);
            compute_nb(A);
            if (!haveB) break;
            int iA = iB + 4;
            haveA = (iA < n);
            if (haveA) load_nb(A, iA);
            compute_nb(Bq);
            i = iA;
        }
    }

    if (lane == 0) sum_s[wid] = wsum;
    {
        float4* arow = (float4*)&accm[wid][0];
        arow[lane]       = make_float4(accre[0], accre[1], accre[2], accre[3]);
        arow[125 + lane] = make_float4(accim[0], accim[1], accim[2], accim[3]);
        if (lane < 61) {
            arow[64 + lane]  = make_float4(accre[4], accre[5], accre[6], accre[7]);
            arow[189 + lane] = make_float4(accim[4], accim[5], accim[6], accim[7]);
        }
    }
    __syncthreads();

    const float S = sum_s[0] + sum_s[1] + sum_s[2] + sum_s[3];
    const float invS = (S > 0.f) ? 1.f / S : 0.f;
    float eta = 0.f;
    if (S > 0.f) {  // has_nbr
        float logf_ = log1pf(freq[anchor]);
        float wv = log1pf(__expf(w_raw_p[0]));  // softplus(w_raw)
        float x = eta_raw_p[0] - wv * logf_ + b_p[0];
        eta = ETA_MAX / (1.f + __expf(-x));
    }

    if (t < 250) {
        const float4* r0 = (const float4*)&accm[0][0];
        const float4* r1 = (const float4*)&accm[1][0];
        const float4* r2 = (const float4*)&accm[2][0];
        const float4* r3 = (const float4*)&accm[3][0];
        float4 a0 = r0[t], a1 = r1[t], a2 = r2[t], a3 = r3[t];
        float4 delta;
        delta.x = (a0.x + a1.x + a2.x + a3.x) * invS;
        delta.y = (a0.y + a1.y + a2.y + a3.y) * invS;
        delta.z = (a0.z + a1.z + a2.z + a3.z) * invS;
        delta.w = (a0.w + a1.w + a2.w + a3.w) * invS;
        const float4* A4 = (const float4*)a_param;
        float4 ap = (t < 125) ? A4[t] : A4[t - 125];
        float4 ei = ((const float4*)(E + (size_t)anchor * TWO_D))[t];
        float4 o;
        // S==0: eta=0 -> out = e_i (matches reference's delta=e_i path)
        o.x = ei.x + eta * (ap.x * delta.x - ei.x);
        o.y = ei.y + eta * (ap.y * delta.y - ei.y);
        o.z = ei.z + eta * (ap.z * delta.z - ei.z);
        o.w = ei.w + eta * (ap.w * delta.w - ei.w);
        ((float4*)(out + (size_t)bid * TWO_D))[t] = o;
    }
}

extern "C" void kernel_launch(void* const* d_in, const int* in_sizes, int n_in,
                              void* d_out, int out_size, void* d_ws, size_t ws_size,
                              hipStream_t stream)
{
    const int*   anchor_ids = (const int*)d_in[0];
    const int*   nbr_ent    = (const int*)d_in[1];
    const int*   nbr_rel    = (const int*)d_in[2];
    const int*   nbr_dir    = (const int*)d_in[3];   // bool -> int32 per harness
    const int*   nbr_mask   = (const int*)d_in[4];   // bool -> int32 per harness
    const float* freq       = (const float*)d_in[5];
    const float* E          = (const float*)d_in[6];
    const float* P          = (const float*)d_in[7];
    const float* a_param    = (const float*)d_in[8];
    const float* eta_raw    = (const float*)d_in[9];
    const float* w_raw      = (const float*)d_in[10];
    const float* b_scalar   = (const float*)d_in[11];
    const float* Wq         = (const float*)d_in[12];
    const float* Wk         = (const float*)d_in[13];
    const float* rel_bias   = (const float*)d_in[14];
    const float* dir_bias   = (const float*)d_in[15];
    float* out = (float*)d_out;

    const int B = in_sizes[0];
    float* M  = (float*)d_ws;                       // B * 1000 floats = 4.1 MB
    float* CS = M + (size_t)B * TWO_D;              // 237 * 1000 floats = 948 KB

    build_trig<<<(NREL * DHALF + 255) / 256, 256, 0, stream>>>(P, CS);
    precompute_m<<<(B + 3) / 4, 256, 0, stream>>>(anchor_ids, E, Wq, Wk, M, B);
    refine<<<B, 256, 0, stream>>>(anchor_ids, nbr_ent, nbr_rel, nbr_dir, nbr_mask,
                                  freq, E, CS, a_param, eta_raw, w_raw, b_scalar,
                                  rel_bias, dir_bias, M, out);
}

// Round 2
// 609.795 us; speedup vs baseline: 1.0278x; 1.0268x over previous
//
#include <hip/hip_runtime.h>
#include <math.h>

#define N_ENT 100000
#define KNBR 64
#define DHALF 500
#define TWO_D 1000
#define ATTN_DIM 128
#define NREL 237
#define ETA_MAX 0.5f

// ---------------------------------------------------------------------------
// Kernel A (merged): blocks [0, nM) compute the per-anchor attention-score
// vector  M[b,:] = (Wk^T (Wq e_i)) / sqrt(ATTN); blocks [nM, nM+463) fill the
// relation cos/sin table CS (948 KB, L2-resident) -- one launch instead of two.
// ---------------------------------------------------------------------------
__global__ __launch_bounds__(256) void precompute_m(
    const int* __restrict__ anchor_ids,
    const float* __restrict__ E,
    const float* __restrict__ Wq,
    const float* __restrict__ Wk,
    const float* __restrict__ P,
    float* __restrict__ CS,
    float* __restrict__ M, int B, int nM)
{
    const int t = threadIdx.x;

    if ((int)blockIdx.x >= nM) {
        // ---- trig-table path (no barriers touched before return) ----
        int idx = ((int)blockIdx.x - nM) * 256 + t;
        if (idx < NREL * DHALF) {
            float s, c;
            sincosf(P[idx], &s, &c);   // precise: matches jnp.cos/sin
            CS[2 * idx]     = c;       // interleaved (cos, sin) per dim
            CS[2 * idx + 1] = s;
        }
        return;
    }

    __shared__ float e_lds[4][TWO_D];     // 16 KB
    __shared__ float qp[2][4][ATTN_DIM];  // 4 KB (two half-d partials)
    __shared__ float q_lds[4][ATTN_DIM];  // 2 KB
    const int b0 = blockIdx.x * 4;

    // stage 4 anchor embeddings (rows are 4000 B, 16B-aligned -> float4)
    for (int j = 0; j < 4; ++j) {
        int bb = b0 + j;
        int row = (bb < B) ? anchor_ids[bb] : 0;
        if (t < 250) {
            float4 v = ((const float4*)(E + (size_t)row * TWO_D))[t];
            ((float4*)&e_lds[j][0])[t] = v;
        }
    }
    __syncthreads();

    // GEMM1: q[j][a] = sum_d e[j][d] * Wq[a][d]; d split into two halves.
    // float4 LDS reads (broadcast, conflict-free): 4x fewer LDS-pipe ops.
    {
        const int a = t & 127;
        const int h = t >> 7;
        float acc[4] = {0.f, 0.f, 0.f, 0.f};
        const float4* wrow4 = (const float4*)(Wq + (size_t)a * TWO_D + h * DHALF);
        const float4* e0 = (const float4*)&e_lds[0][h * DHALF];
        const float4* e1 = (const float4*)&e_lds[1][h * DHALF];
        const float4* e2 = (const float4*)&e_lds[2][h * DHALF];
        const float4* e3 = (const float4*)&e_lds[3][h * DHALF];
        for (int d4 = 0; d4 < DHALF / 4; ++d4) {
            float4 w = wrow4[d4];
            float4 v;
            v = e0[d4]; acc[0] += w.x*v.x + w.y*v.y + w.z*v.z + w.w*v.w;
            v = e1[d4]; acc[1] += w.x*v.x + w.y*v.y + w.z*v.z + w.w*v.w;
            v = e2[d4]; acc[2] += w.x*v.x + w.y*v.y + w.z*v.z + w.w*v.w;
            v = e3[d4]; acc[3] += w.x*v.x + w.y*v.y + w.z*v.z + w.w*v.w;
        }
#pragma unroll
        for (int j = 0; j < 4; ++j) qp[h][j][a] = acc[j];
    }
    __syncthreads();
    for (int idx = t; idx < 4 * ATTN_DIM; idx += 256)
        ((float*)q_lds)[idx] = ((float*)qp)[idx] + ((float*)qp)[4 * ATTN_DIM + idx];
    __syncthreads();

    // GEMM2: m[j][d] = sum_a q[j][a] * Wk[a][d]; thread t owns d = t + 256c
    const float inv_scale = 0.0883883476483184f;  // 1/sqrt(128)
    float acc2[4][4];
#pragma unroll
    for (int c = 0; c < 4; ++c)
#pragma unroll
        for (int j = 0; j < 4; ++j) acc2[c][j] = 0.f;

    for (int a = 0; a < ATTN_DIM; ++a) {
        const float* wkrow = Wk + (size_t)a * TWO_D;
        float wk[4];
#pragma unroll
        for (int c = 0; c < 4; ++c) {
            int d = t + 256 * c;
            wk[c] = (d < TWO_D) ? wkrow[d] : 0.f;  // coalesced
        }
#pragma unroll
        for (int j = 0; j < 4; ++j) {
            float qv = q_lds[j][a];  // LDS broadcast
#pragma unroll
            for (int c = 0; c < 4; ++c) acc2[c][j] += qv * wk[c];
        }
    }
#pragma unroll
    for (int c = 0; c < 4; ++c) {
        int d = t + 256 * c;
        if (d < TWO_D) {
#pragma unroll
            for (int j = 0; j < 4; ++j) {
                int bb = b0 + j;
                if (bb < B) M[(size_t)bb * TWO_D + d] = acc2[c][j] * inv_scale;
            }
        }
    }
}

// ---------------------------------------------------------------------------
// Kernel B: one block per anchor, max-free online softmax (logits O(0.1)).
// v3: register-budget-honest pipeline. Round-1's 2-deep double-buffer needed
// ~190 VGPRs under a 128-VGPR launch_bounds cap -> ~60 spilled regs st/ld per
// neighbor iteration (scratch traffic ate the gains; bench was neutral).
// Now: ONE rotating data buffer (32 VGPRs). Per neighbor: wait+rotate into
// h[] (raw data dies), immediately re-issue next neighbor's 8 float4 loads
// into the SAME registers, then butterfly+exp+accumulate overlap the loads.
// Peak live ~105 VGPRs -> fits the cap, no spill, 16 waves/CU, all 1024
// blocks co-resident.
// ---------------------------------------------------------------------------
__global__ __launch_bounds__(256, 4) void refine(
    const int* __restrict__ anchor_ids,
    const int* __restrict__ nbr_ent,
    const int* __restrict__ nbr_rel,
    const int* __restrict__ nbr_dir,
    const int* __restrict__ nbr_mask,
    const float* __restrict__ freq,
    const float* __restrict__ E,
    const float* __restrict__ CS,
    const float* __restrict__ a_param,
    const float* __restrict__ eta_raw_p,
    const float* __restrict__ w_raw_p,
    const float* __restrict__ b_p,
    const float* __restrict__ rel_bias,
    const float* __restrict__ dir_bias,
    const float* __restrict__ M,
    float* __restrict__ out)
{
    __shared__ float accm[4][TWO_D];   // 16 KB merge buffer
    __shared__ float sum_s[4];
    __shared__ int   ent_c[KNBR];      // compacted metadata: active slots only
    __shared__ int   rel_c[KNBR];
    __shared__ int   dir_c[KNBR];
    __shared__ float bias_c[KNBR];     // rel_bias + dir_bias, precomputed
    __shared__ int   cnt_s;

    const int t = threadIdx.x;
    const int bid = blockIdx.x;
    const int anchor = anchor_ids[bid];
    const int lane = t & 63;
    const int wid = t >> 6;
    const int l1 = (lane < 61) ? lane : 60;  // chunk-1 covers 244 dims = 61 lanes

    // stage + ballot-compact neighbor metadata (wave 0), bias folded in
    if (t < KNBR) {
        size_t off = (size_t)anchor * KNBR + t;
        int e = nbr_ent[off];
        int r = nbr_rel[off];
        int d = nbr_dir[off];
        int m = nbr_mask[off];
        unsigned long long bal = __ballot(m != 0);
        if (m) {
            int j = __popcll(bal & ((1ull << t) - 1));
            ent_c[j] = e;
            rel_c[j] = r;
            dir_c[j] = d;
            bias_c[j] = rel_bias[r] + dir_bias[d];
        }
        if (t == 0) cnt_s = __popcll(bal);
    }

    // lane-local M fragments (row is L2-hot, read by 4 waves)
    const float4* Mr = (const float4*)(M + (size_t)bid * TWO_D);
    float4 mre0 = Mr[lane];
    float4 mim0 = Mr[125 + lane];       // im half starts at float 500 (16B-aligned)
    float4 mre1 = Mr[64 + l1];
    float4 mim1 = Mr[189 + l1];
    if (lane >= 61) {                   // dead chunk-1 lanes contribute 0 to dot
        mre1 = make_float4(0.f, 0.f, 0.f, 0.f);
        mim1 = make_float4(0.f, 0.f, 0.f, 0.f);
    }
    const float mreA[8] = {mre0.x, mre0.y, mre0.z, mre0.w, mre1.x, mre1.y, mre1.z, mre1.w};
    const float mimA[8] = {mim0.x, mim0.y, mim0.z, mim0.w, mim1.x, mim1.y, mim1.z, mim1.w};

    float accre[8], accim[8];
#pragma unroll
    for (int q = 0; q < 8; ++q) { accre[q] = 0.f; accim[q] = 0.f; }
    float wsum = 0.f;

    __syncthreads();
    const int n = cnt_s;

    // single rotating data buffer (32 VGPRs) + per-neighbor scalars
    float4 re0, im0, re1, im1, cA, cB, cC, cD;
    float bias = 0.f, sgn = 1.f;

    auto load_nb = [&](int slot) {
        int df = dir_c[slot];
        const float4* er = (const float4*)(E + (size_t)ent_c[slot] * TWO_D);
        const float4* cr = (const float4*)(CS + (size_t)rel_c[slot] * TWO_D);
        bias = bias_c[slot];
        sgn = df ? -1.f : 1.f;          // RotatE conjugate for reverse edges
        re0 = er[lane];          im0 = er[125 + lane];
        re1 = er[64 + l1];       im1 = er[189 + l1];
        cA = cr[2 * lane];       cB = cr[2 * lane + 1];
        cC = cr[128 + 2 * l1];   cD = cr[129 + 2 * l1];
    };

    int i = wid;
    bool have = (i < n);
    if (have) load_nb(i);
    while (have) {
        // rotate: raw (re,im,cos,sin) die into h[] + dot partial
        float re_[8] = {re0.x, re0.y, re0.z, re0.w, re1.x, re1.y, re1.z, re1.w};
        float im_[8] = {im0.x, im0.y, im0.z, im0.w, im1.x, im1.y, im1.z, im1.w};
        float cc[8]  = {cA.x, cA.z, cB.x, cB.z, cC.x, cC.z, cD.x, cD.z};
        float ssv[8] = {cA.y, cA.w, cB.y, cB.w, cC.y, cC.w, cD.y, cD.w};
        float hre[8], him[8];
        float dot = 0.f;
#pragma unroll
        for (int q = 0; q < 8; ++q) {
            float sv = ssv[q] * sgn;
            hre[q] = re_[q] * cc[q] - im_[q] * sv;
            him[q] = re_[q] * sv + im_[q] * cc[q];
            dot += mreA[q] * hre[q] + mimA[q] * him[q];
        }
        const float biasC = bias;

        // issue next neighbor's loads NOW -- they overlap the butterfly/exp
        // tail below and land in the registers the rotate just freed
        int inext = i + 4;
        have = (inext < n);
        if (have) load_nb(inext);
        i = inext;

        // 64-lane butterfly: every lane gets the full dot
        dot += __shfl_xor(dot, 32);
        dot += __shfl_xor(dot, 16);
        dot += __shfl_xor(dot, 8);
        dot += __shfl_xor(dot, 4);
        dot += __shfl_xor(dot, 2);
        dot += __shfl_xor(dot, 1);

        float p = __expf(dot + biasC);  // |logit| ~ 0.2 -> no max needed
        wsum += p;
#pragma unroll
        for (int q = 0; q < 8; ++q) {
            accre[q] += p * hre[q];
            accim[q] += p * him[q];
        }
    }

    if (lane == 0) sum_s[wid] = wsum;
    {
        float4* arow = (float4*)&accm[wid][0];
        arow[lane]       = make_float4(accre[0], accre[1], accre[2], accre[3]);
        arow[125 + lane] = make_float4(accim[0], accim[1], accim[2], accim[3]);
        if (lane < 61) {
            arow[64 + lane]  = make_float4(accre[4], accre[5], accre[6], accre[7]);
            arow[189 + lane] = make_float4(accim[4], accim[5], accim[6], accim[7]);
        }
    }
    __syncthreads();

    const float S = sum_s[0] + sum_s[1] + sum_s[2] + sum_s[3];
    const float invS = (S > 0.f) ? 1.f / S : 0.f;
    float eta = 0.f;
    if (S > 0.f) {  // has_nbr
        float logf_ = log1pf(freq[anchor]);
        float wv = log1pf(__expf(w_raw_p[0]));  // softplus(w_raw)
        float x = eta_raw_p[0] - wv * logf_ + b_p[0];
        eta = ETA_MAX / (1.f + __expf(-x));
    }

    if (t < 250) {
        const float4* r0 = (const float4*)&accm[0][0];
        const float4* r1 = (const float4*)&accm[1][0];
        const float4* r2 = (const float4*)&accm[2][0];
        const float4* r3 = (const float4*)&accm[3][0];
        float4 a0 = r0[t], a1 = r1[t], a2 = r2[t], a3 = r3[t];
        float4 delta;
        delta.x = (a0.x + a1.x + a2.x + a3.x) * invS;
        delta.y = (a0.y + a1.y + a2.y + a3.y) * invS;
        delta.z = (a0.z + a1.z + a2.z + a3.z) * invS;
        delta.w = (a0.w + a1.w + a2.w + a3.w) * invS;
        const float4* A4 = (const float4*)a_param;
        float4 ap = (t < 125) ? A4[t] : A4[t - 125];
        float4 ei = ((const float4*)(E + (size_t)anchor * TWO_D))[t];
        float4 o;
        // S==0: eta=0 -> out = e_i (matches reference's delta=e_i path)
        o.x = ei.x + eta * (ap.x * delta.x - ei.x);
        o.y = ei.y + eta * (ap.y * delta.y - ei.y);
        o.z = ei.z + eta * (ap.z * delta.z - ei.z);
        o.w = ei.w + eta * (ap.w * delta.w - ei.w);
        ((float4*)(out + (size_t)bid * TWO_D))[t] = o;
    }
}

extern "C" void kernel_launch(void* const* d_in, const int* in_sizes, int n_in,
                              void* d_out, int out_size, void* d_ws, size_t ws_size,
                              hipStream_t stream)
{
    const int*   anchor_ids = (const int*)d_in[0];
    const int*   nbr_ent    = (const int*)d_in[1];
    const int*   nbr_rel    = (const int*)d_in[2];
    const int*   nbr_dir    = (const int*)d_in[3];   // bool -> int32 per harness
    const int*   nbr_mask   = (const int*)d_in[4];   // bool -> int32 per harness
    const float* freq       = (const float*)d_in[5];
    const float* E          = (const float*)d_in[6];
    const float* P          = (const float*)d_in[7];
    const float* a_param    = (const float*)d_in[8];
    const float* eta_raw    = (const float*)d_in[9];
    const float* w_raw      = (const float*)d_in[10];
    const float* b_scalar   = (const float*)d_in[11];
    const float* Wq         = (const float*)d_in[12];
    const float* Wk         = (const float*)d_in[13];
    const float* rel_bias   = (const float*)d_in[14];
    const float* dir_bias   = (const float*)d_in[15];
    float* out = (float*)d_out;

    const int B = in_sizes[0];
    float* M  = (float*)d_ws;                       // B * 1000 floats = 4.1 MB
    float* CS = M + (size_t)B * TWO_D;              // 237 * 1000 floats = 948 KB

    const int nM = (B + 3) / 4;
    const int nT = (NREL * DHALF + 255) / 256;
    precompute_m<<<nM + nT, 256, 0, stream>>>(anchor_ids, E, Wq, Wk, P, CS, M, B, nM);
    refine<<<B, 256, 0, stream>>>(anchor_ids, nbr_ent, nbr_rel, nbr_dir, nbr_mask,
                                  freq, E, CS, a_param, eta_raw, w_raw, b_scalar,
                                  rel_bias, dir_bias, M, out);
}